// Round 14
// baseline (86.941 us; speedup 1.0000x reference)
//
#include <hip/hip_runtime.h>
#include <hip/hip_bf16.h>
#include <cstdint>

typedef __bf16 bf16x8 __attribute__((ext_vector_type(8)));
typedef float f32x4 __attribute__((ext_vector_type(4)));

#define BROWS 4096
#define DH    1024
#define KDIM  2048   // D_IN + D_H
#define NT    32     // K-tiles of 64

// ---------------- fused prep: concat(x,h)->bf16 xh  +  W transpose/interleave->wt ----------------
__global__ __launch_bounds__(256) void k_prep(const float* __restrict__ x,
                                              const float* __restrict__ h,
                                              const float* __restrict__ Wf,
                                              const float* __restrict__ Wi,
                                              const float* __restrict__ Wc,
                                              const float* __restrict__ Wo,
                                              __hip_bfloat16* __restrict__ xh,
                                              __hip_bfloat16* __restrict__ wt) {
  __shared__ float t[64][65];
  const int tid = threadIdx.x;
  if (blockIdx.x < 4096) {
    // concat(x,h) -> bf16 xh[4096][2048], 8 elems/thread
    int64_t idx = ((int64_t)blockIdx.x * 256 + tid) * 8;
    int row = (int)(idx >> 11);
    int col = (int)(idx & 2047);
    const float* src = (col < 1024) ? (x + (int64_t)row * 1024 + col)
                                    : (h + (int64_t)row * 1024 + (col - 1024));
    float4 v0 = reinterpret_cast<const float4*>(src)[0];
    float4 v1 = reinterpret_cast<const float4*>(src)[1];
    alignas(16) __hip_bfloat16 o8[8];
    o8[0] = __float2bfloat16(v0.x); o8[1] = __float2bfloat16(v0.y);
    o8[2] = __float2bfloat16(v0.z); o8[3] = __float2bfloat16(v0.w);
    o8[4] = __float2bfloat16(v1.x); o8[5] = __float2bfloat16(v1.y);
    o8[6] = __float2bfloat16(v1.z); o8[7] = __float2bfloat16(v1.w);
    *reinterpret_cast<int4*>(xh + idx) = *reinterpret_cast<const int4*>(o8);
  } else {
    // W_g[k][j] fp32 -> wt[n'][k] bf16, n' = (j>>4)*64 + g*16 + (j&15)
    const int b = blockIdx.x - 4096;   // 2048 = 4 gates * 16 jt * 32 kt
    const int g  = b & 3;
    const int jt = (b >> 2) & 15;
    const int kt = b >> 6;
    const float* W = (g == 0) ? Wf : (g == 1) ? Wi : (g == 2) ? Wc : Wo;
    const int j0 = jt << 6, k0 = kt << 6;
#pragma unroll
    for (int i = 0; i < 4; ++i) {
      int r = (tid >> 4) + (i << 4);
      int c = (tid & 15) << 2;
      float4 v = *reinterpret_cast<const float4*>(W + (int64_t)(k0 + r) * 1024 + j0 + c);
      t[r][c + 0] = v.x; t[r][c + 1] = v.y; t[r][c + 2] = v.z; t[r][c + 3] = v.w;
    }
    __syncthreads();
#pragma unroll
    for (int i = 0; i < 2; ++i) {
      int task = tid + (i << 8);
      int rr = task >> 3;
      int kc = (task & 7) << 3;
      int np = (((jt << 2) + (rr >> 4)) << 6) + (g << 4) + (rr & 15);
      alignas(16) __hip_bfloat16 o8[8];
#pragma unroll
      for (int e = 0; e < 8; ++e) o8[e] = __float2bfloat16(t[kc + e][rr]);
      *reinterpret_cast<int4*>(wt + (int64_t)np * KDIM + k0 + kc) =
          *reinterpret_cast<const int4*>(o8);
    }
  }
}

// ---------------- fused GEMM + LSTM epilogue: 256x256, 2 barriers/K-tile + counted waits ----------------
__device__ __forceinline__ float sig_(float v) {
  return __builtin_amdgcn_rcpf(1.0f + __expf(-v));
}
__device__ __forceinline__ float tanh_(float v) {
  return fmaf(2.0f, __builtin_amdgcn_rcpf(1.0f + __expf(-2.0f * v)), -1.0f);
}

// LDS regions (bytes): parity p, k-half kh:  A(p,kh) = p*65536 + kh*16384 (256 rows x 64B)
//                                            B(p,kh) = p*65536 + 32768 + kh*16384
// Swizzle: phys 16B-chunk = logical ^ ((row>>1)&3); stage pre-swizzles the global source,
// gload_lds dest linear; asm ds_read XORs the chunk. gload_lds imm offset = 0 always.
#define GLD(PTR, LOFF)                                                           \
  __builtin_amdgcn_global_load_lds(                                              \
      (const __attribute__((address_space(1))) void*)(PTR),                      \
      (__attribute__((address_space(3))) void*)(lds + (LOFF) + wslot), 16, 0, 0)

// stage one unit (256 rows x 32 cols of one matrix, one kh): 2 GLDs
#define STGA(PTR, LOFF)                                                          \
  do { GLD((PTR), (LOFF)); GLD((PTR) + 128 * KDIM, (LOFF) + 4096); } while (0)

#define VM4 asm volatile("s_waitcnt vmcnt(4)" ::: "memory")
#define LG4 asm volatile("s_waitcnt lgkmcnt(4)" ::: "memory")
#define LG0 asm volatile("s_waitcnt lgkmcnt(0)" ::: "memory")
#define SB0 __builtin_amdgcn_sched_barrier(0)
#define BAR __builtin_amdgcn_s_barrier()

// Inline-asm ds_read_b128: not compiler-lgkm-tracked -> counted waits are the only
// gate; SB0 after each wait prevents MFMA hoisting (rule #18).
#define DSR(DST, ABASE, OFF)                                                     \
  asm volatile("ds_read_b128 %0, %1 offset:%2"                                   \
               : "=&v"(DST) : "v"(ABASE), "i"(OFF))

#define RD_AV(BANK, AB, KH, H)                                                   \
  do {                                                                           \
    DSR(BANK[0], AB, (KH) * 16384 + ((H) * 4 + 0) * 1024);                       \
    DSR(BANK[1], AB, (KH) * 16384 + ((H) * 4 + 1) * 1024);                       \
    DSR(BANK[2], AB, (KH) * 16384 + ((H) * 4 + 2) * 1024);                       \
    DSR(BANK[3], AB, (KH) * 16384 + ((H) * 4 + 3) * 1024);                       \
  } while (0)
#define RD_BV(BANK, BB, KH)                                                      \
  do {                                                                           \
    DSR(BANK[0], BB, (KH) * 16384 + 0 * 1024);                                   \
    DSR(BANK[1], BB, (KH) * 16384 + 1 * 1024);                                   \
    DSR(BANK[2], BB, (KH) * 16384 + 2 * 1024);                                   \
    DSR(BANK[3], BB, (KH) * 16384 + 3 * 1024);                                   \
  } while (0)

// 16-MFMA cluster, NO barrier (slip allowed); caller gates with counted lgkm + SB0.
#define MM(BA, BB, H)                                                            \
  do {                                                                           \
    __builtin_amdgcn_s_setprio(1);                                               \
    _Pragma("unroll") for (int i = 0; i < 4; ++i)                                \
      _Pragma("unroll") for (int ni = 0; ni < 4; ++ni)                           \
        acc[(H) * 4 + i][ni] = __builtin_amdgcn_mfma_f32_16x16x32_bf16(          \
            BA[i], BB[ni], acc[(H) * 4 + i][ni], 0, 0, 0);                       \
    __builtin_amdgcn_s_setprio(0);                                               \
  } while (0)

// One K-tile, read byte-bases AB/BB (parity P), stage into elem-base SLP (parity P^1).
// 2 barriers total; counted lgkm gates inside each half; VM4 before each barrier
// retires exactly the 4-GLD group whose region is read right after that barrier.
#define TILE(AB, BB, SLP)                                                        \
  do {                                                                           \
    RD_AV(avA, AB, 0, 0);                                                        \
    RD_BV(bvA, BB, 0);                                                           \
    RD_AV(avB, AB, 0, 1);                                                        \
    STGA(a0, SLP); STGA(b0, (SLP) + 16384);                                      \
    LG4; SB0; MM(avA, bvA, 0);                                                   \
    LG0; SB0; MM(avB, bvA, 1);                                                   \
    VM4; BAR;  /* retires prev-staged kh1 of parity P; releases kh1 reads */     \
    RD_AV(avA, AB, 1, 0);                                                        \
    RD_BV(bvB, BB, 1);                                                           \
    RD_AV(avB, AB, 1, 1);                                                        \
    STGA(a0 + 32, (SLP) + 8192); STGA(b0 + 32, (SLP) + 16384 + 8192);            \
    LG4; SB0; MM(avA, bvB, 0);                                                   \
    LG0; SB0; MM(avB, bvB, 1);                                                   \
    VM4; BAR;  /* retires kh0 of parity P^1; releases next tile's kh0 reads */   \
  } while (0)

#define ADV do { a0 += 64; b0 += 64; } while (0)

__global__ __launch_bounds__(512, 2) void k_lstm_gemm(
    const __hip_bfloat16* __restrict__ xh, const __hip_bfloat16* __restrict__ wt,
    const float* __restrict__ cin,
    const float* __restrict__ bfp, const float* __restrict__ bip,
    const float* __restrict__ bcp, const float* __restrict__ bop,
    float* __restrict__ out) {
  __shared__ __hip_bfloat16 lds[65536];   // 128 KiB
  const int tid  = threadIdx.x;
  const int lane = tid & 63;
  const int wid  = tid >> 6;
  const int wm = wid >> 2, wn = wid & 3;   // 2 x 4 waves; wave output = 128 x 64
  const int wmb = wm << 7, wnb = wn << 6;

  // T1: XCD-chunked bijective swizzle (256 blocks = 8 XCD x 32)
  const int bid  = blockIdx.x;
  const int flat = ((bid & 7) << 5) | (bid >> 3);
  const int m0 = (flat & 15) << 8;
  const int n0 = (flat >> 4) << 8;         // interleaved-gate column space

  f32x4 acc[8][4] = {};                    // [mi][gate] (AGPR)

  // ---- staging addressing: each GLD covers 128 rows x 4 chunks(16B) ----
  const int wslot = wid << 9;
  const int cl = (((lane & 3) ^ ((lane >> 3) & 3)) << 3);
  const __hip_bfloat16* a0 = xh + (int64_t)(m0 + (tid >> 2)) * KDIM + cl;
  const __hip_bfloat16* b0 = wt + (int64_t)(n0 + (tid >> 2)) * KDIM + cl;

  // ---- fragment read base addresses (bytes, lane-constant; per parity/matrix) ----
  const int frow = lane & 15;
  const int rx   = (((lane >> 4) ^ ((frow >> 1) & 3)) << 3);  // swizzled chunk (elems)
  const int aA0 = ((((wmb + frow) << 5) + rx) << 1);          // A parity 0 byte base
  const int aA1 = aA0 + 65536;
  const int bB0 = (((16384 + ((wnb + frow) << 5) + rx)) << 1);// B parity 0 byte base
  const int bB1 = bB0 + 65536;

  bf16x8 avA[4], avB[4], bvA[4], bvB[4];

  // ---- prologue: stage tile0's 4 units into parity 0; retire kh0 units; barrier ----
  STGA(a0, 0);                       // t0 A(kh0)
  STGA(b0, 16384);                   // t0 B(kh0)
  STGA(a0 + 32, 8192);               // t0 A(kh1)
  STGA(b0 + 32, 16384 + 8192);       // t0 B(kh1)
  ADV;                               // pointers -> tile 1
  VM4;                               // kh0 units landed
  BAR;

  for (int t = 0; t < NT; t += 2) {
    TILE(aA0, bB0, 32768);           // tile t   (parity 0), stage tile t+1 -> parity 1
    if (t != 30) ADV;
    TILE(aA1, bB1, 0);               // tile t+1 (parity 1), stage tile t+2 -> parity 0
    ADV;                             // (t=30: dead re-stage of tile 31, in-bounds)
  }
  LG0;                               // safety drain before epilogue

  // ---- fused LSTM epilogue (fp32 outputs: h_new, h_new, c_new) ----
  const int j = (((n0 >> 6) + wn) << 4) + frow;     // h-column in [0,1024)
  const float vbf = bfp[j], vbi = bip[j], vbc = bcp[j], vbo = bop[j];
  const int q4 = (lane >> 4) << 2;
  float* outh1 = out;
  float* outh2 = out + (int64_t)BROWS * DH;
  float* outc  = out + (int64_t)2 * BROWS * DH;
#pragma unroll
  for (int mi = 0; mi < 8; ++mi) {
    const int mbase = m0 + wmb + (mi << 4) + q4;
#pragma unroll
    for (int r = 0; r < 4; ++r) {
      const int m = mbase + r;
      const int64_t idx = (int64_t)m * DH + j;
      float fg = sig_(acc[mi][0][r] + vbf);
      float ig = sig_(acc[mi][1][r] + vbi);
      float cg = tanh_(acc[mi][2][r] + vbc);
      float og = sig_(acc[mi][3][r] + vbo);
      float cn = fg * cin[idx] + ig * cg;
      float hn = og * tanh_(cn);
      outh1[idx] = hn;
      outh2[idx] = hn;
      outc[idx]  = cn;
    }
  }
}

extern "C" void kernel_launch(void* const* d_in, const int* in_sizes, int n_in,
                              void* d_out, int out_size, void* d_ws, size_t ws_size,
                              hipStream_t stream) {
  const float* x  = (const float*)d_in[0];
  const float* h  = (const float*)d_in[1];
  const float* c  = (const float*)d_in[2];
  const float* Wf = (const float*)d_in[3];
  const float* bf = (const float*)d_in[4];
  const float* Wi = (const float*)d_in[5];
  const float* bi = (const float*)d_in[6];
  const float* Wc = (const float*)d_in[7];
  const float* bc = (const float*)d_in[8];
  const float* Wo = (const float*)d_in[9];
  const float* bo = (const float*)d_in[10];
  float* out = (float*)d_out;

  __hip_bfloat16* xh = (__hip_bfloat16*)d_ws;                    // 4096x2048 bf16 (16 MiB)
  __hip_bfloat16* wt = xh + (int64_t)BROWS * KDIM;               // 4096x2048 bf16 (16 MiB)

  hipLaunchKernelGGL(k_prep, dim3(6144), dim3(256), 0, stream,
                     x, h, Wf, Wi, Wc, Wo, xh, wt);
  hipLaunchKernelGGL(k_lstm_gemm, dim3(256), dim3(512), 0, stream,
                     xh, wt, c, bf, bi, bc, bo, out);
}